// Round 2
// baseline (5641.355 us; speedup 1.0000x reference)
//
#include <hip/hip_runtime.h>

#define DEV __device__ __forceinline__

constexpr int Nn  = 50000;
constexpr int Ee  = 800000;
constexpr int Et  = 850000;   // E + N self loops
constexpr int Gg  = 16;
constexpr int Dd  = 64;
constexpr int Hh  = 4;
constexpr int Ll  = 4;
constexpr int INd = 7;
constexpr float NEG  = 0.2f;
constexpr float EPSL = 1e-5f;

DEV float lrelu(float x){ return fmaxf(x, NEG*x); }
DEV float wsum64(float v){
  v += __shfl_xor(v,1); v += __shfl_xor(v,2); v += __shfl_xor(v,4);
  v += __shfl_xor(v,8); v += __shfl_xor(v,16); v += __shfl_xor(v,32);
  return v;
}
DEV void atomicMaxF(float* a, float v){
  if (v >= 0.f) atomicMax((int*)a, __float_as_int(v));
  else          atomicMin((unsigned int*)a, __float_as_uint(v));
}

// ---------------- setup kernels ----------------

__global__ void k_init(int* deg, float* g_sum, float* g_max, int* grp_cnt, float* ea_sum){
  int i = blockIdx.x*256 + threadIdx.x;
  if (i < Nn) deg[i] = 0;
  if (i < Gg*Dd){ g_sum[i] = 0.f; g_max[i] = -3.4e38f; }
  if (i < Gg) grp_cnt[i] = 0;
  if (i < 3) ea_sum[i] = 0.f;
}

__global__ void k_eamean(const float* __restrict__ ea, float* __restrict__ ea_sum){
  __shared__ float ps[4][3];
  int tid = threadIdx.x;
  float s0=0.f, s1=0.f, s2=0.f;
  int stride = gridDim.x * blockDim.x;
  for (int i = blockIdx.x*blockDim.x + tid; i < Ee; i += stride){
    s0 += ea[3*i]; s1 += ea[3*i+1]; s2 += ea[3*i+2];
  }
  s0 = wsum64(s0); s1 = wsum64(s1); s2 = wsum64(s2);
  int wid = tid >> 6;
  if ((tid & 63) == 0){ ps[wid][0]=s0; ps[wid][1]=s1; ps[wid][2]=s2; }
  __syncthreads();
  if (tid == 0){
    atomicAdd(ea_sum+0, ps[0][0]+ps[1][0]+ps[2][0]+ps[3][0]);
    atomicAdd(ea_sum+1, ps[0][1]+ps[1][1]+ps[2][1]+ps[3][1]);
    atomicAdd(ea_sum+2, ps[0][2]+ps[1][2]+ps[2][2]+ps[3][2]);
  }
}

__global__ void k_deg(const int* __restrict__ ei_dst, int* __restrict__ deg){
  int e = blockIdx.x*256 + threadIdx.x;
  if (e >= Et) return;
  int dst = (e < Ee) ? ei_dst[e] : (e - Ee);
  atomicAdd(&deg[dst], 1);
}

__global__ void k_bcnt(const int* __restrict__ batch, int* __restrict__ grp_cnt){
  __shared__ int c[Gg];
  if (threadIdx.x < Gg) c[threadIdx.x] = 0;
  __syncthreads();
  int i = blockIdx.x*256 + threadIdx.x;
  if (i < Nn) atomicAdd(&c[batch[i]], 1);
  __syncthreads();
  if (threadIdx.x < Gg && c[threadIdx.x]) atomicAdd(&grp_cnt[threadIdx.x], c[threadIdx.x]);
}

__global__ __launch_bounds__(1024) void k_scan(
    const int* __restrict__ deg, int* __restrict__ indptr, int* __restrict__ fill,
    const float* __restrict__ ea_sum, float* __restrict__ ea_mean)
{
  __shared__ int tot[1024];
  int tid = threadIdx.x;
  if (tid < 3) ea_mean[tid] = ea_sum[tid] * (1.f/(float)Ee);
  constexpr int CH = (Nn + 1023)/1024;   // 49
  int b0 = tid*CH;
  int loc[CH];
  int s = 0;
  #pragma unroll
  for (int i=0;i<CH;++i){
    int idx = b0+i;
    int d = (idx < Nn) ? deg[idx] : 0;
    loc[i] = s; s += d;
  }
  tot[tid] = s;
  __syncthreads();
  for (int off=1; off<1024; off<<=1){
    int v = (tid>=off) ? tot[tid-off] : 0;
    __syncthreads();
    tot[tid] += v;
    __syncthreads();
  }
  int base = (tid==0) ? 0 : tot[tid-1];
  #pragma unroll
  for (int i=0;i<CH;++i){
    int idx = b0+i;
    if (idx < Nn){
      int ex = base + loc[i];
      fill[idx] = ex;
      indptr[idx+1] = ex + deg[idx];
    }
  }
  if (tid==0) indptr[0] = 0;
}

__global__ void k_scatter(const int* __restrict__ ei_dst, int* __restrict__ fill,
                          int* __restrict__ eidx){
  int e = blockIdx.x*256 + threadIdx.x;
  if (e >= Et) return;
  int dst = (e < Ee) ? ei_dst[e] : (e - Ee);
  int pos = atomicAdd(&fill[dst], 1);
  eidx[pos] = e;
}

// ---------------- encoder ----------------

__global__ __launch_bounds__(256) void k_enc(
    const float* __restrict__ x, const float* __restrict__ W, const float* __restrict__ b,
    float* __restrict__ h)
{
  int i = blockIdx.x*256 + threadIdx.x;
  if (i >= Nn*Dd) return;
  int n = i >> 6, d = i & 63;
  float s = b[d];
  #pragma unroll
  for (int k=0;k<INd;++k) s = fmaf(x[n*INd+k], W[k*Dd+d], s);
  h[i] = s;
}

// ---------------- xl/xr GEMM (+ gate apply from previous layer) ----------------
// block 256 = 4 waves; 32 nodes/block; wave handles 8 nodes x all 512 cols.
// lane covers 8 consecutive cols; cols [0,256)->xl (Wl), [256,512)->xr (Wr).

__global__ __launch_bounds__(256) void k_xlxr(
    float* __restrict__ h, const float* __restrict__ gate, const int* __restrict__ batch,
    const float* __restrict__ Wl, const float* __restrict__ bl,
    const float* __restrict__ Wr, const float* __restrict__ br,
    float* __restrict__ xl, float* __restrict__ xr)
{
  __shared__ float lh[32*68];
  int tid = threadIdx.x;
  int n0 = blockIdx.x * 32;
  for (int r=0; r<8; ++r){
    int idx = r*256 + tid;
    int nl = idx >> 6, d = idx & 63;
    int node = n0 + nl;
    float v = 0.f;
    if (node < Nn){
      v = h[(size_t)node*64 + d];
      if (gate){ v *= gate[batch[node]*64 + d]; h[(size_t)node*64 + d] = v; }
    }
    lh[nl*68 + d] = v;
  }
  __syncthreads();
  int lane = tid & 63;
  int nb = (tid >> 6) * 8;     // local node base of this wave
  int c0 = lane * 8;
  const float* W; const float* bb; float* outp; int col;
  if (c0 < 256){ W = Wl; bb = bl; outp = xl; col = c0; }
  else         { W = Wr; bb = br; outp = xr; col = c0 - 256; }
  float4 bA = *reinterpret_cast<const float4*>(bb + col);
  float4 bB = *reinterpret_cast<const float4*>(bb + col + 4);
  float acc[8][8];
  #pragma unroll
  for (int nq=0; nq<8; ++nq){
    acc[nq][0]=bA.x; acc[nq][1]=bA.y; acc[nq][2]=bA.z; acc[nq][3]=bA.w;
    acc[nq][4]=bB.x; acc[nq][5]=bB.y; acc[nq][6]=bB.z; acc[nq][7]=bB.w;
  }
  for (int d=0; d<64; d+=4){
    float4 wA[4], wB[4];
    #pragma unroll
    for (int dq=0; dq<4; ++dq){
      wA[dq] = *reinterpret_cast<const float4*>(W + (d+dq)*256 + col);
      wB[dq] = *reinterpret_cast<const float4*>(W + (d+dq)*256 + col + 4);
    }
    #pragma unroll
    for (int nq=0; nq<8; ++nq){
      float4 hv = *reinterpret_cast<const float4*>(&lh[(nb+nq)*68 + d]);
      #pragma unroll
      for (int dq=0; dq<4; ++dq){
        float hh = (dq==0)? hv.x : (dq==1)? hv.y : (dq==2)? hv.z : hv.w;
        acc[nq][0] = fmaf(hh, wA[dq].x, acc[nq][0]);
        acc[nq][1] = fmaf(hh, wA[dq].y, acc[nq][1]);
        acc[nq][2] = fmaf(hh, wA[dq].z, acc[nq][2]);
        acc[nq][3] = fmaf(hh, wA[dq].w, acc[nq][3]);
        acc[nq][4] = fmaf(hh, wB[dq].x, acc[nq][4]);
        acc[nq][5] = fmaf(hh, wB[dq].y, acc[nq][5]);
        acc[nq][6] = fmaf(hh, wB[dq].z, acc[nq][6]);
        acc[nq][7] = fmaf(hh, wB[dq].w, acc[nq][7]);
      }
    }
  }
  #pragma unroll
  for (int nq=0; nq<8; ++nq){
    int node = n0 + nb + nq;
    if (node < Nn){
      float4 oA = make_float4(acc[nq][0],acc[nq][1],acc[nq][2],acc[nq][3]);
      float4 oB = make_float4(acc[nq][4],acc[nq][5],acc[nq][6],acc[nq][7]);
      *reinterpret_cast<float4*>(outp + (size_t)node*256 + col)     = oA;
      *reinterpret_cast<float4*>(outp + (size_t)node*256 + col + 4) = oB;
    }
  }
}

// ---------------- fused GATv2 + LN1 + FFN + LN2 + global-latent ----------------
// one wave per node; lane = (head = lane>>4, dim-quad m = lane&15 -> dims m*4..m*4+3).
// online softmax over CSR in-edges; per-node GEMVs via readlane broadcasts.

__global__ __launch_bounds__(256) void k_gat(
    float* __restrict__ h, const float* __restrict__ xl, const float* __restrict__ xr,
    const int* __restrict__ indptr, const int* __restrict__ eidx,
    const int* __restrict__ ei_src, const float* __restrict__ edge_attr,
    const float* __restrict__ ea_mean,
    const float* __restrict__ We, const float* __restrict__ att,
    const float* __restrict__ gatb,
    const float* __restrict__ ln1w, const float* __restrict__ ln1b,
    const float* __restrict__ fW1, const float* __restrict__ fb1,
    const float* __restrict__ fW2, const float* __restrict__ fb2,
    const float* __restrict__ ln2w, const float* __restrict__ ln2b,
    const float* __restrict__ gW1, const float* __restrict__ gb1,
    const float* __restrict__ gW2, const float* __restrict__ gb2,
    const int* __restrict__ batch, float* __restrict__ g_sum, float* __restrict__ g_max)
{
  int lane = threadIdx.x & 63;
  int n = __builtin_amdgcn_readfirstlane(blockIdx.x*4 + (threadIdx.x>>6));
  int coff = (lane>>4)*64 + (lane & 15)*4;

  const float4 xr4 = *reinterpret_cast<const float4*>(xr + (size_t)n*256 + coff);
  const float4 we0 = *reinterpret_cast<const float4*>(We + 0*256 + coff);
  const float4 we1 = *reinterpret_cast<const float4*>(We + 1*256 + coff);
  const float4 we2 = *reinterpret_cast<const float4*>(We + 2*256 + coff);
  const float4 aw  = *reinterpret_cast<const float4*>(att + coff);
  float em0 = ea_mean[0], em1 = ea_mean[1], em2 = ea_mean[2];

  int p0 = indptr[n], p1 = indptr[n+1];
  float mx = -3.4e38f, den = 0.f;
  float a0c=0.f, a1c=0.f, a2c=0.f, a3c=0.f;
  for (int p=p0; p<p1; ++p){
    int e = eidx[p];
    int src; float a0,a1,a2;
    if (e < Ee){ src = ei_src[e]; a0 = edge_attr[3*e]; a1 = edge_attr[3*e+1]; a2 = edge_attr[3*e+2]; }
    else       { src = e - Ee;    a0 = em0; a1 = em1; a2 = em2; }
    float4 xv = *reinterpret_cast<const float4*>(xl + (size_t)src*256 + coff);
    float u0 = xv.x + xr4.x + a0*we0.x + a1*we1.x + a2*we2.x;
    float u1 = xv.y + xr4.y + a0*we0.y + a1*we1.y + a2*we2.y;
    float u2 = xv.z + xr4.z + a0*we0.z + a1*we1.z + a2*we2.z;
    float u3 = xv.w + xr4.w + a0*we0.w + a1*we1.w + a2*we2.w;
    float part = lrelu(u0)*aw.x + lrelu(u1)*aw.y + lrelu(u2)*aw.z + lrelu(u3)*aw.w;
    part += __shfl_xor(part,1); part += __shfl_xor(part,2);
    part += __shfl_xor(part,4); part += __shfl_xor(part,8);
    float m2 = fmaxf(mx, part);
    float sc = __expf(mx - m2);
    float w  = __expf(part - m2);
    den = den*sc + w;
    a0c = a0c*sc + w*xv.x;
    a1c = a1c*sc + w*xv.y;
    a2c = a2c*sc + w*xv.z;
    a3c = a3c*sc + w*xv.w;
    mx = m2;
  }
  float inv = 1.f/(den*(float)Hh);
  float s0=a0c*inv, s1=a1c*inv, s2=a2c*inv, s3=a3c*inv;
  s0 += __shfl_xor(s0,16); s0 += __shfl_xor(s0,32);
  s1 += __shfl_xor(s1,16); s1 += __shfl_xor(s1,32);
  s2 += __shfl_xor(s2,16); s2 += __shfl_xor(s2,32);
  s3 += __shfl_xor(s3,16); s3 += __shfl_xor(s3,32);
  int srcl = lane >> 2;
  float w0 = __shfl(s0, srcl), w1 = __shfl(s1, srcl);
  float w2 = __shfl(s2, srcl), w3 = __shfl(s3, srcl);
  int kk = lane & 3;
  float gat = (kk==0)? w0 : (kk==1)? w1 : (kk==2)? w2 : w3;
  gat += gatb[lane];

  // residual + LN1
  float t = h[(size_t)n*64 + lane] + gat;
  float mean = wsum64(t) * (1.f/64.f);
  float dv = t - mean;
  float var = wsum64(dv*dv) * (1.f/64.f);
  t = dv * rsqrtf(var + EPSL) * ln1w[lane] + ln1b[lane];

  // FFN (64->128->64) via readlane broadcasts
  float hid0 = fb1[lane], hid1 = fb1[64+lane];
  #pragma unroll
  for (int d2=0; d2<64; ++d2){
    float hv = __shfl(t, d2);
    hid0 = fmaf(hv, fW1[d2*128+lane],    hid0);
    hid1 = fmaf(hv, fW1[d2*128+64+lane], hid1);
  }
  hid0 = lrelu(hid0); hid1 = lrelu(hid1);
  float o = fb2[lane];
  #pragma unroll
  for (int j=0; j<64; ++j){
    o = fmaf(__shfl(hid0, j), fW2[j*64+lane],      o);
    o = fmaf(__shfl(hid1, j), fW2[(64+j)*64+lane], o);
  }
  float t2 = t + o;
  mean = wsum64(t2) * (1.f/64.f);
  dv = t2 - mean;
  var = wsum64(dv*dv) * (1.f/64.f);
  float hn = dv * rsqrtf(var + EPSL) * ln2w[lane] + ln2b[lane];
  h[(size_t)n*64 + lane] = hn;

  // global-context latent: lrelu(hn@gW1+gb1)@gW2+gb2
  float u = gb1[lane];
  #pragma unroll
  for (int d2=0; d2<64; ++d2) u = fmaf(__shfl(hn, d2), gW1[d2*64+lane], u);
  u = lrelu(u);
  float lat = gb2[lane];
  #pragma unroll
  for (int j=0; j<64; ++j) lat = fmaf(__shfl(u, j), gW2[j*64+lane], lat);

  int g = batch[n];
  atomicAdd(g_sum + g*64 + lane, lat);
  atomicMaxF(g_max + g*64 + lane, lat);
}

// ---------------- gate (one block), also resets accumulators ----------------

__global__ __launch_bounds__(1024) void k_gate(
    float* __restrict__ g_sum, float* __restrict__ g_max, const int* __restrict__ grp_cnt,
    const float* __restrict__ gW, const float* __restrict__ gb, float* __restrict__ gate)
{
  __shared__ float sme[Gg*64];
  __shared__ float smx[Gg*64];
  int tid = threadIdx.x;
  int g = tid >> 6, d = tid & 63;
  float cnt = fmaxf((float)grp_cnt[g], 1.f);
  sme[tid] = g_sum[tid] / cnt;
  smx[tid] = g_max[tid];
  __syncthreads();
  float a = gb[d];
  #pragma unroll
  for (int j=0;j<64;++j){
    a = fmaf(sme[g*64+j], gW[j*64+d],      a);
    a = fmaf(smx[g*64+j], gW[(64+j)*64+d], a);
  }
  gate[tid] = 1.f/(1.f + __expf(-a));
  g_sum[tid] = 0.f;
  g_max[tid] = -3.4e38f;
}

// ---------------- decoder (applies final gate) ----------------

__global__ __launch_bounds__(256) void k_dec(
    const float* __restrict__ h, const float* __restrict__ gate, const int* __restrict__ batch,
    const float* __restrict__ W1, const float* __restrict__ b1,
    const float* __restrict__ W2, const float* __restrict__ b2,
    float* __restrict__ out)
{
  int lane = threadIdx.x & 63;
  int n = __builtin_amdgcn_readfirstlane(blockIdx.x*4 + (threadIdx.x>>6));
  float hv = h[(size_t)n*64 + lane] * gate[batch[n]*64 + lane];
  float hid = b1[lane];
  #pragma unroll
  for (int d2=0; d2<64; ++d2) hid = fmaf(__shfl(hv,d2), W1[d2*64+lane], hid);
  hid = lrelu(hid);
  float r0 = wsum64(hid * W2[lane*2+0]);
  float r1 = wsum64(hid * W2[lane*2+1]);
  if (lane == 0){
    out[(size_t)n*2]   = r0 + b2[0];
    out[(size_t)n*2+1] = r1 + b2[1];
  }
}

// ---------------- launch ----------------

extern "C" void kernel_launch(void* const* d_in, const int* in_sizes, int n_in,
                              void* d_out, int out_size, void* d_ws, size_t ws_size,
                              hipStream_t stream) {
  const float* x    = (const float*)d_in[0];
  const float* ea   = (const float*)d_in[1];
  const int*   ei   = (const int*)  d_in[2];
  const int*   bat  = (const int*)  d_in[3];
  const float* encW = (const float*)d_in[4];
  const float* encb = (const float*)d_in[5];
  const float* Wl   = (const float*)d_in[6];
  const float* bl   = (const float*)d_in[7];
  const float* Wr   = (const float*)d_in[8];
  const float* br   = (const float*)d_in[9];
  const float* We   = (const float*)d_in[10];
  const float* attw = (const float*)d_in[11];
  const float* gatb = (const float*)d_in[12];
  const float* ln1w = (const float*)d_in[13];
  const float* ln1b = (const float*)d_in[14];
  const float* ln2w = (const float*)d_in[15];
  const float* ln2b = (const float*)d_in[16];
  const float* fW1  = (const float*)d_in[17];
  const float* fb1  = (const float*)d_in[18];
  const float* fW2  = (const float*)d_in[19];
  const float* fb2  = (const float*)d_in[20];
  const float* gW1  = (const float*)d_in[21];
  const float* gb1  = (const float*)d_in[22];
  const float* gW2  = (const float*)d_in[23];
  const float* gb2  = (const float*)d_in[24];
  const float* g2nW = (const float*)d_in[25];
  const float* g2nb = (const float*)d_in[26];
  const float* dW1  = (const float*)d_in[27];
  const float* db1  = (const float*)d_in[28];
  const float* dW2  = (const float*)d_in[29];
  const float* db2  = (const float*)d_in[30];
  float* out = (float*)d_out;

  char* w = (char*)d_ws;
  float* h    = (float*)w; w += (size_t)Nn*64*4;
  float* xl   = (float*)w; w += (size_t)Nn*256*4;
  float* xr   = (float*)w; w += (size_t)Nn*256*4;
  float* gate = (float*)w; w += 1024*4;
  float* gsum = (float*)w; w += 1024*4;
  float* gmax = (float*)w; w += 1024*4;
  float* easum  = (float*)w; w += 16;
  float* eamean = (float*)w; w += 16;
  int* deg    = (int*)w; w += (size_t)Nn*4;
  int* indptr = (int*)w; w += (size_t)(Nn+1)*4;
  int* fill   = (int*)w; w += (size_t)Nn*4;
  int* gcnt   = (int*)w; w += 64;
  int* eidx   = (int*)w; w += (size_t)Et*4;

  const int* ei_src = ei;
  const int* ei_dst = ei + Ee;

  k_init   <<<(Nn+255)/256, 256, 0, stream>>>(deg, gsum, gmax, gcnt, easum);
  k_eamean <<<256, 256, 0, stream>>>(ea, easum);
  k_deg    <<<(Et+255)/256, 256, 0, stream>>>(ei_dst, deg);
  k_bcnt   <<<(Nn+255)/256, 256, 0, stream>>>(bat, gcnt);
  k_scan   <<<1, 1024, 0, stream>>>(deg, indptr, fill, easum, eamean);
  k_scatter<<<(Et+255)/256, 256, 0, stream>>>(ei_dst, fill, eidx);
  k_enc    <<<(Nn*64+255)/256, 256, 0, stream>>>(x, encW, encb, h);

  for (int l=0; l<Ll; ++l){
    k_xlxr<<<(Nn+31)/32, 256, 0, stream>>>(h, l ? gate : nullptr, bat,
        Wl + (size_t)l*64*256, bl + (size_t)l*256,
        Wr + (size_t)l*64*256, br + (size_t)l*256, xl, xr);
    k_gat<<<Nn/4, 256, 0, stream>>>(h, xl, xr, indptr, eidx, ei_src, ea, eamean,
        We + (size_t)l*3*256, attw + (size_t)l*Hh*64, gatb + (size_t)l*64,
        ln1w + (size_t)l*64, ln1b + (size_t)l*64,
        fW1 + (size_t)l*64*128, fb1 + (size_t)l*128,
        fW2 + (size_t)l*128*64, fb2 + (size_t)l*64,
        ln2w + (size_t)l*64, ln2b + (size_t)l*64,
        gW1 + (size_t)l*64*64, gb1 + (size_t)l*64,
        gW2 + (size_t)l*64*64, gb2 + (size_t)l*64,
        bat, gsum, gmax);
    k_gate<<<1, 1024, 0, stream>>>(gsum, gmax, gcnt,
        g2nW + (size_t)l*128*64, g2nb + (size_t)l*64, gate);
  }

  k_dec<<<Nn/4, 256, 0, stream>>>(h, gate, bat, dW1, db1, dW2, db2, out);
}